// Round 7
// baseline (225.100 us; speedup 1.0000x reference)
//
#include <hip/hip_runtime.h>

#define HH 256
#define KK 8

typedef __attribute__((ext_vector_type(8))) short s16x8;
typedef __attribute__((ext_vector_type(4))) float f32x4;
typedef __attribute__((address_space(3))) unsigned int lds_u32;
typedef const __attribute__((address_space(1))) unsigned int glb_u32;

__device__ __forceinline__ float bf2f(unsigned short u){ unsigned x=((unsigned)u)<<16; return __builtin_bit_cast(float,x); }
__device__ __forceinline__ unsigned short f2bf(float f){ unsigned x=__builtin_bit_cast(unsigned,f); return (unsigned short)((x+0x7fffu+((x>>16)&1u))>>16); }
__device__ __forceinline__ float sigmoidf(float x){ return __builtin_amdgcn_rcpf(1.0f + __expf(-x)); }

// ---- K1: all 4 weights f32 -> bf16 in one launch.  grid (32,4) x 256thr ----
__global__ void cvt_w(const float* __restrict__ wa, const float* __restrict__ wu,
                      const float* __restrict__ wv, const float* __restrict__ wbm,
                      unsigned short* __restrict__ dst){
  const int w = blockIdx.y;
  const float* src = (w==0)? wa : (w==1)? wu : (w==2)? wv : wbm;
  const int i = blockIdx.x*256 + threadIdx.x;          // 8192 chunks of 8 per matrix
  const float4* s = reinterpret_cast<const float4*>(src);
  float4 a = s[i*2], b = s[i*2+1];
  uint4 o;
  o.x = (unsigned)f2bf(a.x) | ((unsigned)f2bf(a.y)<<16);
  o.y = (unsigned)f2bf(a.z) | ((unsigned)f2bf(a.w)<<16);
  o.z = (unsigned)f2bf(b.x) | ((unsigned)f2bf(b.y)<<16);
  o.w = (unsigned)f2bf(b.z) | ((unsigned)f2bf(b.w)<<16);
  reinterpret_cast<uint4*>(dst + (size_t)w*65536)[i] = o;
}

// ---- K2: px[m][1024] = prev[m,:] @ [W_A|W_U|W_V|W_B]^T ----
// 512 thr / 8 waves. Block = 128 rows x 1024 cols. A-frags in regs; B-panels
// (128 cols x 128 k, 32KB) double-buffered via global_load_lds; 1 barrier/step.
__global__ __launch_bounds__(512, 4)
void gemm_all(const float* __restrict__ prev,
              const unsigned short* __restrict__ wb,   // [1024][256] bf16 rows = out-cols
              unsigned short* __restrict__ px,         // [N][1024] bf16
              int n)
{
  __shared__ char smem[65536];          // A-stage (64KB) then B dbuf 2x32KB
  const int tid = threadIdx.x;
  const int m0  = blockIdx.x * 128;
  const int lane = tid & 63, wid = tid >> 6;
  const int wr = wid >> 1, wc = wid & 1;     // 4 row-groups(32) x 2 col-halves(64)
  const int lm = lane & 15, kc = lane >> 4;

  // ---- stage A-tile: 128 rows x 256k, f32->bf16, swizzled ----
  #pragma unroll
  for (int it=0; it<8; ++it){
    const int c = it*512 + tid;
    const int row = c>>5, kch = c&31;
    const int gm = m0 + row;
    uint4 o = {0u,0u,0u,0u};
    if (gm < n){
      const float4* sp = reinterpret_cast<const float4*>(prev + (size_t)gm*HH + kch*8);
      float4 f0 = sp[0], f1 = sp[1];
      o.x=(unsigned)f2bf(f0.x)|((unsigned)f2bf(f0.y)<<16);
      o.y=(unsigned)f2bf(f0.z)|((unsigned)f2bf(f0.w)<<16);
      o.z=(unsigned)f2bf(f1.x)|((unsigned)f2bf(f1.y)<<16);
      o.w=(unsigned)f2bf(f1.z)|((unsigned)f2bf(f1.w)<<16);
    }
    *reinterpret_cast<uint4*>(smem + row*512 + ((kch*16) ^ ((row&7)<<4))) = o;
  }
  __syncthreads();

  // ---- A fragments -> registers (wave rows: wr*32 + i*16 + lm) ----
  s16x8 af[2][8];
  #pragma unroll
  for (int i=0;i<2;++i){
    const int row = wr*32 + i*16 + lm;
    #pragma unroll
    for (int k8=0;k8<8;++k8)
      af[i][k8] = *reinterpret_cast<const s16x8*>(smem + row*512 + ((k8*64 + kc*16) ^ ((row&7)<<4)));
  }
  __syncthreads();        // all af reads done; smem reusable as B buffers

  // per-lane pre-swizzled DMA source offset (rule #21: inverse-swz source, linear dest)
  const int rr = lane>>4, ks16 = (lane&15)*16;
  const int off_e = rr*512 + (ks16 ^ (rr<<4));     // chunks with row0%8==0; odd chunks: ^64
  const char* wbc = reinterpret_cast<const char*>(wb);

  // panel = 128 out-cols x 128k: global base Wp; LDS dest lb (linear)
  #define ISSUE_PANEL(Wp, lb)                                                      \
    { _Pragma("unroll")                                                            \
      for (int c_=0;c_<4;++c_){                                                    \
        const int chunk_ = wid*4 + c_;                                             \
        const char* ga_ = (Wp) + chunk_*2048 + ((c_&1)? (off_e^64) : off_e);       \
        __builtin_amdgcn_global_load_lds((glb_u32*)ga_,                            \
            (lds_u32*)((lb) + chunk_*1024), 16, 0, 0);                             \
      } }

  ISSUE_PANEL(wbc, smem)                 // panel (g=0, kh=0) -> buf0

  f32x4 acc[2][4];
  for (int g=0; g<8; ++g){
    #pragma unroll
    for (int kh=0; kh<2; ++kh){
      __syncthreads();                   // drains DMA: panel (g,kh) resident in buf[kh]
      if (kh==0){
        ISSUE_PANEL(wbc + g*65536 + 256, smem + 32768)        // (g,1) -> buf1
      } else if (g < 7){
        ISSUE_PANEL(wbc + (g+1)*65536, smem)                  // (g+1,0) -> buf0
      }
      if (kh==0){
        #pragma unroll
        for (int i=0;i<2;++i)
          #pragma unroll
          for (int j=0;j<4;++j) acc[i][j]=(f32x4){0.f,0.f,0.f,0.f};
      }
      const char* rb = smem + kh*32768;
      #pragma unroll
      for (int kk=0; kk<4; ++kk){
        #pragma unroll
        for (int j=0;j<4;++j){
          const int brow = wc*64 + j*16 + lm;
          s16x8 bf = *reinterpret_cast<const s16x8*>(rb + brow*256 + ((kk*64 + kc*16) ^ ((brow&7)<<4)));
          acc[0][j] = __builtin_amdgcn_mfma_f32_16x16x32_bf16(af[0][kh*4+kk], bf, acc[0][j], 0, 0, 0);
          acc[1][j] = __builtin_amdgcn_mfma_f32_16x16x32_bf16(af[1][kh*4+kk], bf, acc[1][j], 0, 0, 0);
        }
      }
      if (kh==1){                        // flush this g's 128 cols
        #pragma unroll
        for (int i=0;i<2;++i){
          #pragma unroll
          for (int r=0;r<4;++r){
            const int gm = m0 + wr*32 + i*16 + kc*4 + r;    // D: row=(lane>>4)*4+reg
            if (gm < n){
              unsigned short* dp = px + (size_t)gm*1024 + g*128 + wc*64 + lm;
              #pragma unroll
              for (int j=0;j<4;++j) dp[j*16] = f2bf(acc[i][j][r]);
            }
          }
        }
      }
    }
  }
  #undef ISSUE_PANEL
}

// ---- K3: gather epilogue. 32 lanes per node-row, 8 cols/lane. ----
__global__ __launch_bounds__(256)
void epilogue(const unsigned short* __restrict__ px,   // [N][4][256]: A,U,V,B
              const int* __restrict__ parent,
              const int* __restrict__ child,
              const int* __restrict__ mask,
              float* __restrict__ out,
              int n)
{
  const int e = blockIdx.x*8 + (threadIdx.x>>5);
  if (e >= n) return;
  const int c8 = (threadIdx.x & 31) * 8;
  const int p  = parent[e];

  const unsigned short* rp = px + (size_t)p*1024 + c8;
  uint4 av = *reinterpret_cast<const uint4*>(rp);         // PA
  uint4 uv = *reinterpret_cast<const uint4*>(rp + 256);   // PU
  const unsigned short* ap = reinterpret_cast<const unsigned short*>(&av);
  const unsigned short* up = reinterpret_cast<const unsigned short*>(&uv);

  float A[8], o[8], eta[8];
  #pragma unroll
  for (int j=0;j<8;++j){ A[j]=bf2f(ap[j]); o[j]=bf2f(up[j]); eta[j]=0.f; }

  int nm = 0;
  #pragma unroll
  for (int k=0;k<KK;++k){
    if (mask[(size_t)e*KK + k]){
      const unsigned short* rc = px + (size_t)child[(size_t)e*KK + k]*1024 + c8;
      uint4 pv = *reinterpret_cast<const uint4*>(rc + 512);   // PV
      uint4 pb = *reinterpret_cast<const uint4*>(rc + 768);   // PB
      const unsigned short* vp = reinterpret_cast<const unsigned short*>(&pv);
      const unsigned short* bp = reinterpret_cast<const unsigned short*>(&pb);
      #pragma unroll
      for (int j=0;j<8;++j){
        o[j]   += bf2f(vp[j]);
        eta[j] += sigmoidf(A[j] + bf2f(bp[j]));
      }
    } else ++nm;
  }

  const float fnm = (float)nm;
  #pragma unroll
  for (int j=0;j<8;++j){
    float s = o[j] + eta[j] + fnm * sigmoidf(A[j]);
    out[(size_t)p*HH + c8 + j] = s > 0.f ? s : 0.f;
  }
}

extern "C" void kernel_launch(void* const* d_in, const int* in_sizes, int n_in,
                              void* d_out, int out_size, void* d_ws, size_t ws_size,
                              hipStream_t stream)
{
  const float* prev = (const float*)d_in[0];
  const float* W_U  = (const float*)d_in[1];
  const float* W_V  = (const float*)d_in[2];
  const float* W_A  = (const float*)d_in[3];
  const float* W_B  = (const float*)d_in[4];
  const int* parent = (const int*)d_in[5];
  const int* child  = (const int*)d_in[6];
  const int* mask   = (const int*)d_in[7];
  float* out = (float*)d_out;

  const int n_nodes = in_sizes[5];

  unsigned short* wb = (unsigned short*)d_ws;      // [1024][256] bf16 (A,U,V,B rows)
  unsigned short* px = wb + 4*65536;               // [N][1024] bf16

  dim3 gc(32, 4);
  cvt_w<<<gc, 256, 0, stream>>>(W_A, W_U, W_V, W_B, wb);

  gemm_all<<<(n_nodes + 127)/128, 512, 0, stream>>>(prev, wb, px, n_nodes);

  epilogue<<<(n_nodes + 7)/8, 256, 0, stream>>>(px, parent, child, mask, out, n_nodes);
}